// Round 6
// baseline (132.758 us; speedup 1.0000x reference)
//
#include <hip/hip_runtime.h>
#include <math.h>

// img (8, 3, 1024, 2048) fp32 -> same-shape fp32 output.
// Barrier-free design: one wave owns one (strip, row-chunk, plane) tile.
// 9 column strips; wave covers 256 cols (64 lanes x 4), valid-lane decay
// img(0..63) -> grad(1..62) -> hmax/vmax(2..61) -> hmin/out(3..60) = 232 cols.
#define Wd 2048
#define Hd 1024
#define BC 24
#define CH 64                 // output rows per wave (y0 % 8 == 0)
#define STRIPS 9
#define CHUNKS (Hd / CH)      // 16
#define WPP (STRIPS * CHUNKS) // 144 waves per plane
#define NWAVES (WPP * BC)     // 3456
#define NT 256                // 4 waves per block (blocks are irrelevant: no barriers)

__device__ __forceinline__ float4 f4s(float v) { return make_float4(v, v, v, v); }

// Exact-equivalent rewrite of the reference masking (verified rounds 4-5, absmax 0).
__device__ __forceinline__ float masked_grad1(float g1, float g2, float g3) {
    const float HALF_T     = (float)(0.5 / 1023.0);
    const float GRD_BOTTOM = (float)(1.0 / 1023.0);
    const float GRD_UP     = (float)(4.0 / 1023.0);
    const float THIRD      = (float)(1.0 / 3.0);
    float m  = (g1 + g2 + g3) * THIRD;
    float lo = m - HALF_T;
    float hi = m + HALF_T;
    float a  = fabsf(g1);
    bool keep = (g1 >= lo) & (g1 <= hi) & (a >= GRD_BOTTOM) & (a <= GRD_UP);
    return keep ? g1 : 0.0f;
}

__device__ __forceinline__ float4 shflup1(float4 v) {
    float4 r;
    r.x = __shfl_up(v.x, 1, 64); r.y = __shfl_up(v.y, 1, 64);
    r.z = __shfl_up(v.z, 1, 64); r.w = __shfl_up(v.w, 1, 64);
    return r;
}
__device__ __forceinline__ float4 shfldn1(float4 v) {
    float4 r;
    r.x = __shfl_down(v.x, 1, 64); r.y = __shfl_down(v.y, 1, 64);
    r.z = __shfl_down(v.z, 1, 64); r.w = __shfl_down(v.w, 1, 64);
    return r;
}

struct State {
    float4 im[8];   // img rows: row r lives in im[r & 7]
    float4 vp[2];   // global prefetch, row r in vp[r & 1] (2 rows in flight)
    float4 g[2];    // grad ring (body-parity indexed)
    float4 hr[2];   // hmax ring
    float4 vr[2];   // vmax ring
    float4 nr[2];   // hmin ring
};

// One pipeline row, same skew as the verified round-5 kernel:
//   load row L+2 (2-deep prefetch), grad row L-3, hmax row L-4,
//   vmax row L-5, hmin row L-6, out row L-7.  LM8 == L & 7 (compile-time).
// CE: this wave's strip touches the left/right image edge (lv = lane col-valid).
// RE: this wave's chunk touches the top/bottom image edge.
template<int LM8, bool CE, bool RE, bool STORE>
__device__ __forceinline__ void row_body(
        int L, State& S, const float* __restrict__ ip, float* __restrict__ op,
        bool lv, bool sv) {
    constexpr int IW = LM8 & 7;
    constexpr int PW = LM8 & 1;
    constexpr int PR = (LM8 + 1) & 1;

    // consume prefetched row L; issue row L+2
    float4 v = S.vp[PW];
    S.im[IW] = v;
    {
        int Ln = L + 2;
        float4 nv = f4s(0.f);
        bool ok = true;
        if (RE) ok = (unsigned)Ln < (unsigned)Hd;
        if (CE) ok = ok && lv;
        if (ok) nv = *(const float4*)(ip + (size_t)Ln * Wd);
        S.vp[PW] = nv;
    }

    // ---- gradient row L-3 (x-halo via intra-wave shfl; zero-pad comes from
    //      halo lanes holding 0.0 in CE strips / neighbor data otherwise) ----
    float4 ce = S.im[(LM8 + 5) & 7];          // row L-3
    float4 lf = shflup1(ce);                  // lane-1 cols (c0-4..c0-1)
    float4 rt = shfldn1(ce);                  // lane+1 cols (c0+4..c0+7)
    float4 rA = S.im[(LM8 + 6) & 7];          // row L-2
    float4 rB = S.im[(LM8 + 4) & 7];          // row L-4
    float4 rC = S.im[(LM8 + 7) & 7];          // row L-1
    float4 rD = S.im[(LM8 + 3) & 7];          // row L-5
    float4 rE = v;                            // row L
    float4 rF = S.im[(LM8 + 2) & 7];          // row L-6

    float4 gv;
    {
        const float K = 255.75f;  // 1023/4 exact
        float gx0 = masked_grad1(ce.y - lf.w, ce.z - lf.z, ce.w - lf.y);
        float gx1 = masked_grad1(ce.z - ce.x, ce.w - lf.w, rt.x - lf.z);
        float gx2 = masked_grad1(ce.w - ce.y, rt.x - ce.x, rt.y - lf.w);
        float gx3 = masked_grad1(rt.x - ce.z, rt.y - ce.y, rt.z - ce.x);
        float gy0 = masked_grad1(rA.x - rB.x, rC.x - rD.x, rE.x - rF.x);
        float gy1 = masked_grad1(rA.y - rB.y, rC.y - rD.y, rE.y - rF.y);
        float gy2 = masked_grad1(rA.z - rB.z, rC.z - rD.z, rE.z - rF.z);
        float gy3 = masked_grad1(rA.w - rB.w, rC.w - rD.w, rE.w - rF.w);
        gv.x = fmaxf(fabsf(gx0), fabsf(gy0)) * K;
        gv.y = fmaxf(fabsf(gx1), fabsf(gy1)) * K;
        gv.z = fmaxf(fabsf(gx2), fabsf(gy2)) * K;
        gv.w = fmaxf(fabsf(gx3), fabsf(gy3)) * K;
    }
    if (CE) { if (!lv) gv = f4s(-INFINITY); }   // dilation pad at image cols

    // ---- hmax row L-4 (g[PR] = grad row L-4) ----
    float4 gp = S.g[PR];
    float gl = __shfl_up(gp.w, 1, 64);
    float gr = __shfl_down(gp.x, 1, 64);
    float4 hm;
    hm.x = fmaxf(fmaxf(gl,   gp.x), gp.y);
    hm.y = fmaxf(fmaxf(gp.x, gp.y), gp.z);
    hm.z = fmaxf(fmaxf(gp.y, gp.z), gp.w);
    hm.w = fmaxf(fmaxf(gp.z, gp.w), gr);
    if (RE) { if ((unsigned)(L - 4) >= (unsigned)Hd) hm = f4s(-INFINITY); }

    // ---- vmax row L-5 = max(hmax rows L-6, L-5, L-4) ----
    float4 h6 = S.hr[PW];
    float4 h5 = S.hr[PR];
    float4 vm;
    vm.x = fmaxf(fmaxf(h6.x, h5.x), hm.x);
    vm.y = fmaxf(fmaxf(h6.y, h5.y), hm.y);
    vm.z = fmaxf(fmaxf(h6.z, h5.z), hm.z);
    vm.w = fmaxf(fmaxf(h6.w, h5.w), hm.w);
    if (RE) { if ((unsigned)(L - 5) >= (unsigned)Hd) vm = f4s(INFINITY); }
    if (CE) { if (!lv) vm = f4s(INFINITY); }    // erosion pad at image cols
    S.hr[PW] = hm;

    // ---- hmin row L-6 (vr[PR] = vmax row L-6) ----
    float4 vq = S.vr[PR];
    float vl  = __shfl_up(vq.w, 1, 64);
    float vr_ = __shfl_down(vq.x, 1, 64);
    float4 hn;
    hn.x = fminf(fminf(vl,   vq.x), vq.y);
    hn.y = fminf(fminf(vq.x, vq.y), vq.z);
    hn.z = fminf(fminf(vq.y, vq.z), vq.w);
    hn.w = fminf(fminf(vq.z, vq.w), vr_);
    S.vr[PW] = vm;

    // ---- out row L-7 = min(hmin rows L-8, L-7, L-6) ----
    if (STORE) {
        float4 n8 = S.nr[PW];
        float4 n7 = S.nr[PR];
        float4 o;
        o.x = fminf(fminf(n8.x, n7.x), hn.x);
        o.y = fminf(fminf(n8.y, n7.y), hn.y);
        o.z = fminf(fminf(n8.z, n7.z), hn.z);
        o.w = fminf(fminf(n8.w, n7.w), hn.w);
        if (sv) *(float4*)(op + (size_t)(L - 7) * Wd) = o;
    }
    S.nr[PW] = hn;
    S.g[PW]  = gv;
}

template<bool CE, bool RE>
__device__ __forceinline__ void run_sweep(
        const float* __restrict__ ip, float* __restrict__ op, int y0,
        bool lv, bool sv) {
    State S;
    #pragma unroll
    for (int i = 0; i < 8; ++i) S.im[i] = f4s(0.f);
    S.g[0] = S.g[1] = f4s(0.f);
    S.hr[0] = S.hr[1] = f4s(-INFINITY);
    S.vr[0] = S.vr[1] = f4s(INFINITY);
    S.nr[0] = S.nr[1] = f4s(INFINITY);

    // ---- prime: rows y0-6 .. y0-1 into im slots (y0 % 8 == 0) ----
    #pragma unroll
    for (int r = 0; r < 6; ++r) {
        int row = y0 - 6 + r;
        float4 v = f4s(0.f);
        bool ok = true;
        if (RE) ok = (unsigned)row < (unsigned)Hd;
        if (CE) ok = ok && lv;
        if (ok) v = *(const float4*)(ip + (size_t)row * Wd);
        S.im[(r + 2) & 7] = v;
    }
    {   // prefetch rows y0, y0+1 (always in-image rows)
        float4 a = f4s(0.f), b = f4s(0.f);
        if (!CE || lv) {
            a = *(const float4*)(ip + (size_t)y0 * Wd);
            b = *(const float4*)(ip + (size_t)(y0 + 1) * Wd);
        }
        S.vp[0] = a; S.vp[1] = b;
    }

    // ---- warm-up: 7 bodies, no store ----
    row_body<0, CE, RE, false>(y0 + 0, S, ip, op, lv, sv);
    row_body<1, CE, RE, false>(y0 + 1, S, ip, op, lv, sv);
    row_body<2, CE, RE, false>(y0 + 2, S, ip, op, lv, sv);
    row_body<3, CE, RE, false>(y0 + 3, S, ip, op, lv, sv);
    row_body<4, CE, RE, false>(y0 + 4, S, ip, op, lv, sv);
    row_body<5, CE, RE, false>(y0 + 5, S, ip, op, lv, sv);
    row_body<6, CE, RE, false>(y0 + 6, S, ip, op, lv, sv);

    // ---- steady: CH bodies, always store ----
    #pragma unroll 1
    for (int jj = 0; jj < CH; jj += 8) {
        const int Lb = y0 + 7 + jj;   // Lb % 8 == 7
        row_body<7, CE, RE, true>(Lb + 0, S, ip, op, lv, sv);
        row_body<0, CE, RE, true>(Lb + 1, S, ip, op, lv, sv);
        row_body<1, CE, RE, true>(Lb + 2, S, ip, op, lv, sv);
        row_body<2, CE, RE, true>(Lb + 3, S, ip, op, lv, sv);
        row_body<3, CE, RE, true>(Lb + 4, S, ip, op, lv, sv);
        row_body<4, CE, RE, true>(Lb + 5, S, ip, op, lv, sv);
        row_body<5, CE, RE, true>(Lb + 6, S, ip, op, lv, sv);
        row_body<6, CE, RE, true>(Lb + 7, S, ip, op, lv, sv);
    }
}

__global__ __launch_bounds__(NT, 4) void gradmap_wave_kernel(
        const float* __restrict__ img, float* __restrict__ out) {
    const int tid  = threadIdx.x;
    const int lane = tid & 63;
    const int wv   = tid >> 6;
    const int flat = blockIdx.x * (NT / 64) + wv;   // wave id 0..NWAVES-1

    const int plane = flat / WPP;
    const int rem   = flat - plane * WPP;
    const int chunk = rem / STRIPS;
    const int strip = rem - chunk * STRIPS;

    // strips 0..7: output cols [232s, 232s+232); strip 8: [1816, 2048)
    const int base = (strip < 8) ? strip * 232 - 12 : 1804;
    const int y0 = chunk * CH;
    const int gc0 = base + 4 * lane;                // this lane's first img col

    const bool lv = (unsigned)gc0 < (unsigned)Wd;   // lane's cols inside image
    const bool sv = (lane >= 3) && (lane <= 60);    // lanes that own output cols

    const float* ip = img + (size_t)plane * Hd * Wd + gc0;
    float*       op = out + (size_t)plane * Hd * Wd + gc0;

    const bool colEdge = (strip == 0) | (strip == STRIPS - 1);
    const bool rowEdge = (chunk == 0) | (chunk == CHUNKS - 1);

    if (!colEdge && !rowEdge)      run_sweep<false, false>(ip, op, y0, lv, sv);
    else if (colEdge && !rowEdge)  run_sweep<true,  false>(ip, op, y0, lv, sv);
    else if (!colEdge && rowEdge)  run_sweep<false, true >(ip, op, y0, lv, sv);
    else                           run_sweep<true,  true >(ip, op, y0, lv, sv);
}

extern "C" void kernel_launch(void* const* d_in, const int* in_sizes, int n_in,
                              void* d_out, int out_size, void* d_ws, size_t ws_size,
                              hipStream_t stream) {
    const float* img = (const float*)d_in[0];
    float* out = (float*)d_out;
    dim3 grid(NWAVES / (NT / 64));   // 864 blocks x 4 waves = 3456 waves
    dim3 block(NT);
    gradmap_wave_kernel<<<grid, block, 0, stream>>>(img, out);
}